// Round 8
// baseline (485.848 us; speedup 1.0000x reference)
//
#include <hip/hip_runtime.h>
#include <hip/hip_bf16.h>

#define B_  2
#define S_  2048
#define D_  2048
#define H_  16
#define DH_ 128
#define NH_ 64   // K strips of 32: 2048/32

typedef __attribute__((ext_vector_type(8))) short bf16x8;
typedef __attribute__((ext_vector_type(4))) float f32x4;
typedef __attribute__((address_space(3))) short lshort;

__device__ inline short bf16bits(float v) {
    __hip_bfloat16 h = __float2bfloat16(v);
    return *reinterpret_cast<short*>(&h);
}

// ---------------------------------------------------------------------------
// fp32 -> bf16 cast, 8 elements/thread.
// ---------------------------------------------------------------------------
__global__ __launch_bounds__(256)
void f2b_kernel(const float* __restrict__ in, __hip_bfloat16* __restrict__ out)
{
    const size_t i = ((size_t)blockIdx.x * 256 + threadIdx.x) * 8;
    float4 a = *(const float4*)(in + i);
    float4 b = *(const float4*)(in + i + 4);
    short s[8] = { bf16bits(a.x), bf16bits(a.y), bf16bits(a.z), bf16bits(a.w),
                   bf16bits(b.x), bf16bits(b.y), bf16bits(b.z), bf16bits(b.w) };
    *(uint4*)(out + i) = *(const uint4*)s;
}

// three weights in one launch (per-block pointer select)
__global__ __launch_bounds__(256)
void f2b3_kernel(const float* __restrict__ i0, const float* __restrict__ i1,
                 const float* __restrict__ i2, __hip_bfloat16* __restrict__ o0,
                 __hip_bfloat16* __restrict__ o1, __hip_bfloat16* __restrict__ o2,
                 int per)
{
    const int sel = blockIdx.x / per, rem = blockIdx.x % per;
    const float* in = sel == 0 ? i0 : (sel == 1 ? i1 : i2);
    __hip_bfloat16* out = sel == 0 ? o0 : (sel == 1 ? o1 : o2);
    const size_t i = ((size_t)rem * 256 + threadIdx.x) * 8;
    float4 a = *(const float4*)(in + i);
    float4 b = *(const float4*)(in + i + 4);
    short s[8] = { bf16bits(a.x), bf16bits(a.y), bf16bits(a.z), bf16bits(a.w),
                   bf16bits(b.x), bf16bits(b.y), bf16bits(b.z), bf16bits(b.w) };
    *(uint4*)(out + i) = *(const uint4*)s;
}

__device__ inline void async16(const __hip_bfloat16* g, short* l) {
    __builtin_amdgcn_global_load_lds(
        (const __attribute__((address_space(1))) void*)g,
        (__attribute__((address_space(3))) void*)l, 16, 0, 0);
}

// asm ds_read_b128: invisible to the compiler's waitcnt insertion (round-5:
// plain LDS loads made hipcc insert vmcnt(0) per strip against the DMA ring).
#define DSR(dst, base, imm) \
    asm volatile("ds_read_b128 %0, %1 offset:" #imm : "=v"(dst) : "v"(base))

// ---------------------------------------------------------------------------
// Counted-vmcnt GEMM core v4: BM=BN=128, K strips of 32, 4 waves (256 thr),
// wave tile 64x64 (acc 4x4), ONE barrier per strip.
//
// Round-7 analysis: at 2 blocks/CU x 8 waves the kernel is LDS-read-BW
// bound (per strip per CU: 128 ds_read_b128 = 512 cyc at 256 B/cyc vs 307
// cyc MFMA) and only 2 blocks to overlap barriers -> 27% MfmaUtil. v4
// shrinks the block to 48 KB LDS -> 3 blocks/CU: per-CU LDS traffic drops
// to 384 cyc vs 230 MFMA, and 3 independent blocks absorb each other's
// barrier/vmcnt stalls (m114 mechanism that carried the round-4 153 us
// kernel, which had conflicts and vmcnt(0) drains; this has neither).
//
// Ring-3, stage lead 2, 4 loads per strip stage (2 A + 2 B):
//   end-of-strip-s wait: outstanding <= {s+1, s+2} = 8 loads; vmcnt(4)
//   retires s+1 exactly. Tail: vmcnt(0). WAR: slot (s+2)%3 last read at
//   strip s-1, barrier-separated.
//
// Bank-conflict-free layout (verified rounds 5-7: SQ_LDS_BANK_CONFLICT=0):
// strip = 128 rows x 32 cols; within each 8-row block granule-major
// phys = g*8 + (row&7); stage source pre-swizzled to match (rule 21).
// Stage decode from linear slot l (= tid for rows 0-63, tid+256 for rows
// 64-127): row = (l>>5)*8 + (l&7), granule = (l>>3)&3.
// ---------------------------------------------------------------------------
__device__ __forceinline__ void gemm8_main(
    const __hip_bfloat16* __restrict__ Ap,
    const __hip_bfloat16* __restrict__ Bp,
    int arow0, int brow0,
    short* sA, short* sB, f32x4 (&acc)[4][4])
{
    const int tid  = threadIdx.x;
    const int w    = tid >> 6;        // 0..3
    const int lane = tid & 63;
    const int l15  = lane & 15;
    const int quad = lane >> 4;
    const int wm   = w >> 1;          // 0..1
    const int wn   = w & 1;           // 0..1

    // stage decode (linear DMA slot -> pre-swizzled global source)
    const int srow = ((tid >> 5) << 3) | (tid & 7);   // 0..63 (load 0)
    const int sg   = (tid >> 3) & 3;                  // granule 0..3
    const __hip_bfloat16* aS0 = Ap + (size_t)(arow0 + srow) * D_ + sg * 8;
    const __hip_bfloat16* aS1 = aS0 + (size_t)64 * D_;   // rows 64..127
    const __hip_bfloat16* bS0 = Bp + (size_t)(brow0 + srow) * D_ + sg * 8;
    const __hip_bfloat16* bS1 = bS0 + (size_t)64 * D_;
    short* aD = sA + (w << 9);   // wave-uniform LDS dest (lane*16B implicit)
    short* bD = sB + (w << 9);

    // per-lane read base: 256*(l15>>3) + 64*quad + 8*(l15&7) shorts
    const int rb = ((l15 >> 3) << 8) + ((((quad << 3) | (l15 & 7))) << 3);

#define STAGE_A(sl) do { short* d_ = aD + (sl) * 4096;              \
        async16(aS0 + sA_off, d_);                                  \
        async16(aS1 + sA_off, d_ + 2048); } while (0)
#define STAGE_B(sl) do { short* d_ = bD + (sl) * 4096;              \
        async16(bS0 + sB_off, d_);                                  \
        async16(bS1 + sB_off, d_ + 2048); } while (0)

    // prologue: strips 0,1 -> slots 0,1 (8 loads); vmcnt(4): strip 0 landed
    {
        size_t sA_off = 0, sB_off = 0;
        STAGE_A(0); STAGE_B(0);
        sA_off = 32;  sB_off = 32;
        STAGE_A(1); STAGE_B(1);
    }
    asm volatile("s_waitcnt vmcnt(4)" ::: "memory");
    __builtin_amdgcn_s_barrier();

    int sl = 0;        // read slot = s % 3
    int stg = 2;       // stage slot = (s+2) % 3
    for (int s = 0; s < NH_; ++s) {
        const lshort* sa3 = (const lshort*)(sA + sl * 4096 + wm * 2048 + rb);
        const lshort* sb3 = (const lshort*)(sB + sl * 4096 + wn * 2048 + rb);

        // issue order matters for the counted lgkm waits: b0..b3,a0,a1 first
        bf16x8 a0, a1, a2, a3, b0, b1, b2, b3;
        DSR(b0, sb3, 0); DSR(b1, sb3, 1024);
        DSR(b2, sb3, 2048); DSR(b3, sb3, 3072);
        DSR(a0, sa3, 0); DSR(a1, sa3, 1024);
        DSR(a2, sa3, 2048); DSR(a3, sa3, 3072);

        if (s + 2 < NH_) {
            const size_t sA_off = (size_t)(s + 2) * 32;
            const size_t sB_off = (size_t)(s + 2) * 32;
            STAGE_A(stg); STAGE_B(stg);
        }

        // cluster 1: needs b0..b3,a0,a1 (a2,a3 still in flight)
        asm volatile("s_waitcnt lgkmcnt(2)" ::: "memory");
        __builtin_amdgcn_sched_barrier(0);
        __builtin_amdgcn_s_setprio(1);
        acc[0][0] = __builtin_amdgcn_mfma_f32_16x16x32_bf16(a0, b0, acc[0][0], 0, 0, 0);
        acc[0][1] = __builtin_amdgcn_mfma_f32_16x16x32_bf16(a0, b1, acc[0][1], 0, 0, 0);
        acc[0][2] = __builtin_amdgcn_mfma_f32_16x16x32_bf16(a0, b2, acc[0][2], 0, 0, 0);
        acc[0][3] = __builtin_amdgcn_mfma_f32_16x16x32_bf16(a0, b3, acc[0][3], 0, 0, 0);
        acc[1][0] = __builtin_amdgcn_mfma_f32_16x16x32_bf16(a1, b0, acc[1][0], 0, 0, 0);
        acc[1][1] = __builtin_amdgcn_mfma_f32_16x16x32_bf16(a1, b1, acc[1][1], 0, 0, 0);
        acc[1][2] = __builtin_amdgcn_mfma_f32_16x16x32_bf16(a1, b2, acc[1][2], 0, 0, 0);
        acc[1][3] = __builtin_amdgcn_mfma_f32_16x16x32_bf16(a1, b3, acc[1][3], 0, 0, 0);
        __builtin_amdgcn_s_setprio(0);
        __builtin_amdgcn_sched_barrier(0);

        // cluster 2: a2,a3
        asm volatile("s_waitcnt lgkmcnt(0)" ::: "memory");
        __builtin_amdgcn_sched_barrier(0);
        __builtin_amdgcn_s_setprio(1);
        acc[2][0] = __builtin_amdgcn_mfma_f32_16x16x32_bf16(a2, b0, acc[2][0], 0, 0, 0);
        acc[2][1] = __builtin_amdgcn_mfma_f32_16x16x32_bf16(a2, b1, acc[2][1], 0, 0, 0);
        acc[2][2] = __builtin_amdgcn_mfma_f32_16x16x32_bf16(a2, b2, acc[2][2], 0, 0, 0);
        acc[2][3] = __builtin_amdgcn_mfma_f32_16x16x32_bf16(a2, b3, acc[2][3], 0, 0, 0);
        acc[3][0] = __builtin_amdgcn_mfma_f32_16x16x32_bf16(a3, b0, acc[3][0], 0, 0, 0);
        acc[3][1] = __builtin_amdgcn_mfma_f32_16x16x32_bf16(a3, b1, acc[3][1], 0, 0, 0);
        acc[3][2] = __builtin_amdgcn_mfma_f32_16x16x32_bf16(a3, b2, acc[3][2], 0, 0, 0);
        acc[3][3] = __builtin_amdgcn_mfma_f32_16x16x32_bf16(a3, b3, acc[3][3], 0, 0, 0);
        __builtin_amdgcn_s_setprio(0);
        __builtin_amdgcn_sched_barrier(0);

        if (s + 2 < NH_) asm volatile("s_waitcnt vmcnt(4)" ::: "memory");
        else             asm volatile("s_waitcnt vmcnt(0)" ::: "memory");
        __builtin_amdgcn_s_barrier();

        sl  = (sl  == 2) ? 0 : sl + 1;
        stg = (stg == 2) ? 0 : stg + 1;
    }
#undef STAGE_A
#undef STAGE_B
}

// ---------------------------------------------------------------------------
// Merged QKV GEMM. 1536 blocks (3 GEMMs x 512) = 2 exact fill rounds at
// 3 blocks/CU; bijective XCD swizzle (1536 % 8 == 0).
//   nsel 0/1 (q/k): A=xb rows, B=w rows, coalesced bf16 stores.
//   nsel 2 (v) OPERAND-SWAPPED (A=wv, B=xb) so vt stores are coalesced.
// ---------------------------------------------------------------------------
__global__ __launch_bounds__(256)
void gemm_qkv8(const __hip_bfloat16* __restrict__ xb,
               const __hip_bfloat16* __restrict__ wq,
               const __hip_bfloat16* __restrict__ wk,
               const __hip_bfloat16* __restrict__ wv,
               __hip_bfloat16* __restrict__ q,
               __hip_bfloat16* __restrict__ k,
               __hip_bfloat16* __restrict__ vt)
{
    __shared__ __align__(16) short sA[3 * 4096];   // 24 KB
    __shared__ __align__(16) short sB[3 * 4096];   // 24 KB

    const int rbk = (int)blockIdx.x;
    const int bid = (rbk & 7) * 192 + (rbk >> 3);  // XCD chunking
    const int nsel = bid >> 9;                     // 0,1,2
    const int t    = bid & 511;
    int marow0, n0;
    const __hip_bfloat16 *Ap, *Bp;
    if (nsel < 2) {
        marow0 = (t >> 4) * 128;          // over 4096 x-rows
        n0     = (t & 15) * 128;          // over 2048 w-rows
        Ap = xb; Bp = nsel ? wk : wq;
    } else {
        marow0 = (t >> 5) * 128;          // over 2048 wv-rows
        n0     = (t & 31) * 128;          // over 4096 x-rows
        Ap = wv; Bp = xb;
    }

    f32x4 acc[4][4];
    #pragma unroll
    for (int i = 0; i < 4; i++)
        #pragma unroll
        for (int j = 0; j < 4; j++) acc[i][j] = (f32x4)(0.0f);

    gemm8_main(Ap, Bp, marow0, n0, sA, sB, acc);

    const int tid = threadIdx.x, w = tid >> 6, lane = tid & 63;
    const int l15 = lane & 15, quad = lane >> 4;
    const int wm = w >> 1, wn = w & 1;

    #pragma unroll
    for (int mf = 0; mf < 4; mf++) {
        #pragma unroll
        for (int r = 0; r < 4; r++) {
            const int m = marow0 + wm * 64 + mf * 16 + quad * 4 + r;
            #pragma unroll
            for (int nf = 0; nf < 4; nf++) {
                const int n = n0 + wn * 64 + nf * 16 + l15;
                if (nsel < 2) {
                    const int b = m >> 11, s = m & 2047;
                    const int h = n >> 7,  dh = n & 127;
                    __hip_bfloat16* o = nsel ? k : q;
                    o[(((size_t)(b * 16 + h)) * 2048 + s) * 128 + dh] =
                        __float2bfloat16(acc[mf][nf][r]);
                } else {
                    const int h = m >> 7,  dh = m & 127;
                    const int b = n >> 11, sq = n & 2047;
                    vt[(((size_t)(b * 16 + h)) * 128 + dh) * 2048 + sq] =
                        __float2bfloat16(acc[mf][nf][r]);
                }
            }
        }
    }
}

// ---------------------------------------------------------------------------
// Final projection: out[M,N] fp32 = vals[M,K] * Wo[N,K]^T. 512 blocks
// (2 per CU in one round).
// ---------------------------------------------------------------------------
__global__ __launch_bounds__(256)
void gemm_o8(const __hip_bfloat16* __restrict__ A,
             const __hip_bfloat16* __restrict__ W,
             float* __restrict__ out)
{
    __shared__ __align__(16) short sA[3 * 4096];
    __shared__ __align__(16) short sB[3 * 4096];

    const int rbk = (int)blockIdx.x;
    const int bid = (rbk & 7) * 64 + (rbk >> 3);   // 512 % 8 == 0
    const int marow0 = (bid >> 4) * 128;   // over 4096 rows
    const int n0     = (bid & 15) * 128;   // over 2048 cols

    f32x4 acc[4][4];
    #pragma unroll
    for (int i = 0; i < 4; i++)
        #pragma unroll
        for (int j = 0; j < 4; j++) acc[i][j] = (f32x4)(0.0f);

    gemm8_main(A, W, marow0, n0, sA, sB, acc);

    const int tid = threadIdx.x, w = tid >> 6, lane = tid & 63;
    const int l15 = lane & 15, quad = lane >> 4;
    const int wm = w >> 1, wn = w & 1;

    #pragma unroll
    for (int mf = 0; mf < 4; mf++) {
        #pragma unroll
        for (int r = 0; r < 4; r++) {
            const int m = marow0 + wm * 64 + mf * 16 + quad * 4 + r;
            #pragma unroll
            for (int nf = 0; nf < 4; nf++) {
                const int n = n0 + wn * 64 + nf * 16 + l15;
                out[(size_t)m * 2048 + n] = acc[mf][nf][r];
            }
        }
    }
}

// ---------------------------------------------------------------------------
// RoPE on q AND k in one launch; cos/sin fp32 [S, DH].
// ---------------------------------------------------------------------------
__global__ __launch_bounds__(256)
void rope2_kernel(__hip_bfloat16* __restrict__ q, __hip_bfloat16* __restrict__ k,
                  const float* __restrict__ cos_, const float* __restrict__ sin_,
                  int per)
{
    const int sel = blockIdx.x / per, rem = blockIdx.x % per;
    __hip_bfloat16* base = sel == 0 ? q : k;
    const size_t i = (size_t)rem * blockDim.x + threadIdx.x;
    const int dh = (int)(i & 63);
    const size_t row = i >> 6;
    const int s = (int)(row % S_);
    __hip_bfloat16* p = base + row * DH_;

    const float x1 = __bfloat162float(p[dh]);
    const float x2 = __bfloat162float(p[dh + 64]);
    const float c1 = cos_[s * DH_ + dh];
    const float s1 = sin_[s * DH_ + dh];
    const float c2 = cos_[s * DH_ + dh + 64];
    const float s2 = sin_[s * DH_ + dh + 64];

    p[dh]      = __float2bfloat16(x1 * c1 - x2 * s1);
    p[dh + 64] = __float2bfloat16(x2 * c2 + x1 * s2);
}

// ---------------------------------------------------------------------------
// Flash attention v4 (unchanged): 64-row q-tiles, kv-tile 64, DMA-staged
// double-buffered LDS (zero-VGPR prefetch), XOR swizzle both sides,
// 1024 blocks longest-first.
// ---------------------------------------------------------------------------
#define PSTR 72

__global__ __launch_bounds__(256)
void attn_mfma(const __hip_bfloat16* __restrict__ q,
               const __hip_bfloat16* __restrict__ k,
               const __hip_bfloat16* __restrict__ vt,
               __hip_bfloat16* __restrict__ vals)
{
    __shared__ __align__(16) short sK[2 * 64 * 128];
    __shared__ __align__(16) short sV[2 * 128 * 64];
    __shared__ __align__(16) short sP[4 * 16 * PSTR];

    const int idx   = (int)blockIdx.x;
    const int bh    = idx & 31;
    const int qtile = 31 - (idx >> 5);
    const int q0    = qtile * 64;
    const int tid   = threadIdx.x;
    const int w     = tid >> 6;
    const int lane  = tid & 63;
    const int l15   = lane & 15;
    const int quad  = lane >> 4;
    const int qb    = q0 + w * 16;

    bf16x8 qf[4];
    {
        const __hip_bfloat16* qrow =
            q + ((size_t)bh * S_ + qb + l15) * DH_ + quad * 8;
        #pragma unroll
        for (int c = 0; c < 4; c++)
            qf[c] = *(const bf16x8*)(qrow + c * 32);
    }

    f32x4 o[8];
    #pragma unroll
    for (int d = 0; d < 8; d++) o[d] = (f32x4)(0.0f);
    float mrow[4], lrow[4];
    #pragma unroll
    for (int r = 0; r < 4; r++) { mrow[r] = -1e30f; lrow[r] = 0.f; }

    const float scale = 0.08838834764831845f;
    const int niter = qtile + 1;

    const int krow_in = lane >> 4, kgran = lane & 15;
    const int vrow_in = lane >> 3, vgran = lane & 7;

    auto stage = [&](int bsel, int kv0) {
        short* kb = sK + bsel * 8192;
        short* vb = sV + bsel * 8192;
        #pragma unroll
        for (int t = 0; t < 4; t++) {
            const int c    = w * 4 + t;
            const int krow = c * 4 + krow_in;
            const int kcol = (kgran * 16) ^ ((krow & 7) << 4);
            async16(k + ((size_t)bh * S_ + kv0 + krow) * DH_ + (kcol >> 1),
                    kb + c * 512);
            const int vrow = c * 8 + vrow_in;
            const int vcol = (vgran * 16) ^ ((vrow & 7) << 4);
            async16(vt + ((size_t)bh * DH_ + vrow) * S_ + kv0 + (vcol >> 1),
                    vb + c * 512);
        }
    };

    stage(0, 0);
    __syncthreads();

    int buf = 0;
    for (int it = 0; it < niter; ++it) {
        const int kv0 = it * 64;

        if (it + 1 < niter) stage(buf ^ 1, kv0 + 64);

        const short* kb = sK + buf * 8192;
        const short* vb = sV + buf * 8192;
        const int xsw = (l15 & 7) << 3;

        f32x4 s[4];
        #pragma unroll
        for (int n = 0; n < 4; n++) s[n] = (f32x4)(0.0f);
        #pragma unroll
        for (int n = 0; n < 4; n++) {
            const short* kp = kb + (n * 16 + l15) * 128;
            #pragma unroll
            for (int c = 0; c < 4; c++) {
                bf16x8 kf = *(const bf16x8*)(kp + ((quad * 8 + c * 32) ^ xsw));
                s[n] = __builtin_amdgcn_mfma_f32_16x16x32_bf16(qf[c], kf, s[n], 0, 0, 0);
            }
        }

        {
            const bool msk = (kv0 + 63 > qb);
            float sv[4][4];
            #pragma unroll
            for (int n = 0; n < 4; n++)
                #pragma unroll
                for (int r = 0; r < 4; r++) {
                    float x = s[n][r] * scale;
                    if (msk) {
                        const int kvg = kv0 + n * 16 + l15;
                        const int qg  = qb + quad * 4 + r;
                        if (kvg > qg) x = -1e30f;
                    }
                    sv[n][r] = x;
                }

            float alpha[4];
            #pragma unroll
            for (int r = 0; r < 4; r++) {
                float v = fmaxf(fmaxf(sv[0][r], sv[1][r]), fmaxf(sv[2][r], sv[3][r]));
                #pragma unroll
                for (int m2 = 8; m2; m2 >>= 1)
                    v = fmaxf(v, __shfl_xor(v, m2, 64));
                const float mn = fmaxf(mrow[r], v);
                alpha[r] = __expf(mrow[r] - mn);
                mrow[r] = mn;
            }
            #pragma unroll
            for (int r = 0; r < 4; r++) {
                float rs = 0.f;
                #pragma unroll
                for (int n = 0; n < 4; n++) {
                    const float p = __expf(sv[n][r] - mrow[r]);
                    sv[n][r] = p;
                    rs += p;
                }
                lrow[r] = lrow[r] * alpha[r] + rs;
            }
            #pragma unroll
            for (int d = 0; d < 8; d++)
                #pragma unroll
                for (int r = 0; r < 4; r++)
                    o[d][r] *= alpha[r];

            short* pb = &sP[(w * 16) * PSTR];
            #pragma unroll
            for (int n = 0; n < 4; n++)
                #pragma unroll
                for (int r = 0; r < 4; r++)
                    pb[(quad * 4 + r) * PSTR + n * 16 + l15] = bf16bits(sv[n][r]);
        }

        #pragma unroll
        for (int c = 0; c < 2; c++) {
            bf16x8 pf = *(const bf16x8*)(&sP[(w * 16 + l15) * PSTR + c * 32 + quad * 8]);
            #pragma unroll
            for (int d = 0; d < 8; d++) {
                bf16x8 vf = *(const bf16x8*)(vb + (d * 16 + l15) * 64 +
                                             ((quad * 8 + c * 32) ^ xsw));
                o[d] = __builtin_amdgcn_mfma_f32_16x16x32_bf16(pf, vf, o[d], 0, 0, 0);
            }
        }
        __syncthreads();
        buf ^= 1;
    }

    const int b = bh >> 4, h = bh & 15;
    #pragma unroll
    for (int r = 0; r < 4; r++) {
        float l = lrow[r];
        #pragma unroll
        for (int m2 = 8; m2; m2 >>= 1)
            l += __shfl_xor(l, m2, 64);
        const float inv = 1.0f / l;
        const int qg = qb + quad * 4 + r;
        #pragma unroll
        for (int d = 0; d < 8; d++) {
            const int col = d * 16 + l15;
            vals[(((size_t)b * S_ + qg) * H_ + h) * DH_ + col] =
                __float2bfloat16(o[d][r] * inv);
        }
    }
}

// ---------------------------------------------------------------------------
extern "C" void kernel_launch(void* const* d_in, const int* in_sizes, int n_in,
                              void* d_out, int out_size, void* d_ws, size_t ws_size,
                              hipStream_t stream)
{
    const float* x    = (const float*)d_in[0];
    const float* cos_ = (const float*)d_in[1];
    const float* sin_ = (const float*)d_in[2];
    const float* Wq   = (const float*)d_in[3];
    const float* Wk   = (const float*)d_in[4];
    const float* Wv   = (const float*)d_in[5];
    const float* Wo   = (const float*)d_in[6];
    float* out = (float*)d_out;

    const size_t NELEM = (size_t)B_ * S_ * D_;       // 8388608
    const size_t WELEM = (size_t)D_ * D_;            // 4194304

    // d_out scratch during QKV phase: 3 bf16 weights (25.2 MB <= 33.5 MB)
    __hip_bfloat16* wqb = (__hip_bfloat16*)d_out;
    __hip_bfloat16* wkb = wqb + WELEM;
    __hip_bfloat16* wvb = wkb + WELEM;
    // ws (67 MB): q,k,vt,vals. xb shares the vals region (dead before attn
    // writes vals); Wo-bf16 reuses q region (dead after attn).
    __hip_bfloat16* q    = (__hip_bfloat16*)d_ws;
    __hip_bfloat16* k    = q + NELEM;
    __hip_bfloat16* vt   = k + NELEM;
    __hip_bfloat16* vals = vt + NELEM;
    __hip_bfloat16* xb   = vals;
    __hip_bfloat16* wob  = q;

    const int xcb = (int)(NELEM / (256 * 8));        // 4096 blocks
    const int wcb = (int)(WELEM / (256 * 8));        // 2048 blocks

    f2b_kernel<<<xcb, 256, 0, stream>>>(x, xb);
    f2b3_kernel<<<3 * wcb, 256, 0, stream>>>(Wq, Wk, Wv, wqb, wkb, wvb, wcb);

    // 3 GEMMs x 512 blocks = 1536 = 2 exact fill rounds at 3 blocks/CU
    gemm_qkv8<<<1536, 256, 0, stream>>>(xb, wqb, wkb, wvb, q, k, vt);

    const int rope_blocks = B_ * H_ * S_ * 64 / 256;  // per tensor
    rope2_kernel<<<2 * rope_blocks, 256, 0, stream>>>(q, k, cos_, sin_, rope_blocks);

    // 32 qtiles x 32 bh, longest-first for LPT backfill
    attn_mfma<<<dim3(32 * (B_ * H_)), 256, 0, stream>>>(q, k, vt, vals);

    f2b_kernel<<<wcb, 256, 0, stream>>>(Wo, wob);
    gemm_o8<<<512, 256, 0, stream>>>(vals, wob, out);
}

// Round 9
// 427.632 us; speedup vs baseline: 1.1361x; 1.1361x over previous
//
#include <hip/hip_runtime.h>
#include <hip/hip_bf16.h>

#define B_  2
#define S_  2048
#define D_  2048
#define H_  16
#define DH_ 128
#define NH_ 64   // K strips of 32: 2048/32

typedef __attribute__((ext_vector_type(8))) short bf16x8;
typedef __attribute__((ext_vector_type(4))) float f32x4;
typedef __attribute__((address_space(3))) short lshort;

__device__ inline short bf16bits(float v) {
    __hip_bfloat16 h = __float2bfloat16(v);
    return *reinterpret_cast<short*>(&h);
}

// ---------------------------------------------------------------------------
// fp32 -> bf16 cast, 8 elements/thread.
// ---------------------------------------------------------------------------
__global__ __launch_bounds__(256)
void f2b_kernel(const float* __restrict__ in, __hip_bfloat16* __restrict__ out)
{
    const size_t i = ((size_t)blockIdx.x * 256 + threadIdx.x) * 8;
    float4 a = *(const float4*)(in + i);
    float4 b = *(const float4*)(in + i + 4);
    short s[8] = { bf16bits(a.x), bf16bits(a.y), bf16bits(a.z), bf16bits(a.w),
                   bf16bits(b.x), bf16bits(b.y), bf16bits(b.z), bf16bits(b.w) };
    *(uint4*)(out + i) = *(const uint4*)s;
}

// three weights in one launch (per-block pointer select)
__global__ __launch_bounds__(256)
void f2b3_kernel(const float* __restrict__ i0, const float* __restrict__ i1,
                 const float* __restrict__ i2, __hip_bfloat16* __restrict__ o0,
                 __hip_bfloat16* __restrict__ o1, __hip_bfloat16* __restrict__ o2,
                 int per)
{
    const int sel = blockIdx.x / per, rem = blockIdx.x % per;
    const float* in = sel == 0 ? i0 : (sel == 1 ? i1 : i2);
    __hip_bfloat16* out = sel == 0 ? o0 : (sel == 1 ? o1 : o2);
    const size_t i = ((size_t)rem * 256 + threadIdx.x) * 8;
    float4 a = *(const float4*)(in + i);
    float4 b = *(const float4*)(in + i + 4);
    short s[8] = { bf16bits(a.x), bf16bits(a.y), bf16bits(a.z), bf16bits(a.w),
                   bf16bits(b.x), bf16bits(b.y), bf16bits(b.z), bf16bits(b.w) };
    *(uint4*)(out + i) = *(const uint4*)s;
}

__device__ inline void async16(const __hip_bfloat16* g, short* l) {
    __builtin_amdgcn_global_load_lds(
        (const __attribute__((address_space(1))) void*)g,
        (__attribute__((address_space(3))) void*)l, 16, 0, 0);
}

// asm ds_read_b128: invisible to the compiler's waitcnt insertion (round-5:
// plain LDS loads made hipcc insert vmcnt(0) per strip against the DMA ring).
#define DSR(dst, base, imm) \
    asm volatile("ds_read_b128 %0, %1 offset:" #imm : "=v"(dst) : "v"(base))

// ---------------------------------------------------------------------------
// Counted-vmcnt GEMM core (round-7 exact, best measured: 158 us qkv, 0 bank
// conflicts, no spill). BM=128 x BN=256, K strips of 32, 8 waves (512 thr),
// wave tile 64x64, ONE barrier per strip. Ring-3, stage lead 2.
// Round-8 regression note: shrinking to 128^2/4-wave halved operand reuse
// (FETCH 146->273 MB) and regressed 158->200 us. This config is frozen.
// ---------------------------------------------------------------------------
__device__ __forceinline__ void gemm8_main(
    const __hip_bfloat16* __restrict__ Ap,
    const __hip_bfloat16* __restrict__ Bp,
    int arow0, int brow0,
    short* sA, short* sB, f32x4 (&acc)[4][4])
{
    const int tid  = threadIdx.x;
    const int w    = tid >> 6;
    const int lane = tid & 63;
    const int l15  = lane & 15;
    const int quad = lane >> 4;
    const int wm   = w >> 2;
    const int wn   = w & 3;

    // stage decode (linear DMA slot -> pre-swizzled global source)
    const int srow = ((tid >> 5) << 3) | (tid & 7);   // 0..127
    const int sg   = (tid >> 3) & 3;                  // granule 0..3
    const __hip_bfloat16* aS  = Ap + (size_t)(arow0 + srow) * D_ + sg * 8;
    const __hip_bfloat16* bS0 = Bp + (size_t)(brow0 + srow) * D_ + sg * 8;
    const __hip_bfloat16* bS1 = bS0 + (size_t)128 * D_;
    short* aD = sA + (w << 9);   // wave-uniform LDS dest (lane*16B implicit)
    short* bD = sB + (w << 9);

    // per-lane read base: 256*(l15>>3) + 64*quad + 8*(l15&7) shorts
    const int rb = ((l15 >> 3) << 8) + ((((quad << 3) | (l15 & 7))) << 3);

#define STAGE_A8(sl) async16(aS + sA_off, aD + (sl) * 4096)
#define STAGE_B8(sl) do { short* d_ = bD + (sl) * 8192;             \
        async16(bS0 + sB_off, d_);                                  \
        async16(bS1 + sB_off, d_ + 4096); } while (0)

    // prologue: strips 0,1 -> slots 0,1 (6 loads); vmcnt(3): strip 0 landed
    {
        size_t sA_off = 0, sB_off = 0;
        STAGE_A8(0); STAGE_B8(0);
        sA_off = 32;  sB_off = 32;
        STAGE_A8(1); STAGE_B8(1);
    }
    asm volatile("s_waitcnt vmcnt(3)" ::: "memory");
    __builtin_amdgcn_s_barrier();

    int sl = 0;        // read slot = s % 3
    int stg = 2;       // stage slot = (s+2) % 3
    for (int s = 0; s < NH_; ++s) {
        const lshort* sa3 = (const lshort*)(sA + sl * 4096 + wm * 2048 + rb);
        const lshort* sb3 = (const lshort*)(sB + sl * 8192 + wn * 2048 + rb);

        // issue order matters for the counted lgkm waits: b0..b3,a0,a1 first
        bf16x8 a0, a1, a2, a3, b0, b1, b2, b3;
        DSR(b0, sb3, 0); DSR(b1, sb3, 1024);
        DSR(b2, sb3, 2048); DSR(b3, sb3, 3072);
        DSR(a0, sa3, 0); DSR(a1, sa3, 1024);
        DSR(a2, sa3, 2048); DSR(a3, sa3, 3072);

        if (s + 2 < NH_) {
            const size_t sA_off = (size_t)(s + 2) * 32;
            const size_t sB_off = (size_t)(s + 2) * 32;
            STAGE_A8(stg); STAGE_B8(stg);
        }

        // cluster 1: needs b0..b3,a0,a1 (a2,a3 still in flight)
        asm volatile("s_waitcnt lgkmcnt(2)" ::: "memory");
        __builtin_amdgcn_sched_barrier(0);
        __builtin_amdgcn_s_setprio(1);
        acc[0][0] = __builtin_amdgcn_mfma_f32_16x16x32_bf16(a0, b0, acc[0][0], 0, 0, 0);
        acc[0][1] = __builtin_amdgcn_mfma_f32_16x16x32_bf16(a0, b1, acc[0][1], 0, 0, 0);
        acc[0][2] = __builtin_amdgcn_mfma_f32_16x16x32_bf16(a0, b2, acc[0][2], 0, 0, 0);
        acc[0][3] = __builtin_amdgcn_mfma_f32_16x16x32_bf16(a0, b3, acc[0][3], 0, 0, 0);
        acc[1][0] = __builtin_amdgcn_mfma_f32_16x16x32_bf16(a1, b0, acc[1][0], 0, 0, 0);
        acc[1][1] = __builtin_amdgcn_mfma_f32_16x16x32_bf16(a1, b1, acc[1][1], 0, 0, 0);
        acc[1][2] = __builtin_amdgcn_mfma_f32_16x16x32_bf16(a1, b2, acc[1][2], 0, 0, 0);
        acc[1][3] = __builtin_amdgcn_mfma_f32_16x16x32_bf16(a1, b3, acc[1][3], 0, 0, 0);
        __builtin_amdgcn_s_setprio(0);
        __builtin_amdgcn_sched_barrier(0);

        // cluster 2: a2,a3
        asm volatile("s_waitcnt lgkmcnt(0)" ::: "memory");
        __builtin_amdgcn_sched_barrier(0);
        __builtin_amdgcn_s_setprio(1);
        acc[2][0] = __builtin_amdgcn_mfma_f32_16x16x32_bf16(a2, b0, acc[2][0], 0, 0, 0);
        acc[2][1] = __builtin_amdgcn_mfma_f32_16x16x32_bf16(a2, b1, acc[2][1], 0, 0, 0);
        acc[2][2] = __builtin_amdgcn_mfma_f32_16x16x32_bf16(a2, b2, acc[2][2], 0, 0, 0);
        acc[2][3] = __builtin_amdgcn_mfma_f32_16x16x32_bf16(a2, b3, acc[2][3], 0, 0, 0);
        acc[3][0] = __builtin_amdgcn_mfma_f32_16x16x32_bf16(a3, b0, acc[3][0], 0, 0, 0);
        acc[3][1] = __builtin_amdgcn_mfma_f32_16x16x32_bf16(a3, b1, acc[3][1], 0, 0, 0);
        acc[3][2] = __builtin_amdgcn_mfma_f32_16x16x32_bf16(a3, b2, acc[3][2], 0, 0, 0);
        acc[3][3] = __builtin_amdgcn_mfma_f32_16x16x32_bf16(a3, b3, acc[3][3], 0, 0, 0);
        __builtin_amdgcn_s_setprio(0);
        __builtin_amdgcn_sched_barrier(0);

        if (s + 2 < NH_) asm volatile("s_waitcnt vmcnt(3)" ::: "memory");
        else             asm volatile("s_waitcnt vmcnt(0)" ::: "memory");
        __builtin_amdgcn_s_barrier();

        sl  = (sl  == 2) ? 0 : sl + 1;
        stg = (stg == 2) ? 0 : stg + 1;
    }
#undef STAGE_A8
#undef STAGE_B8
}

// ---------------------------------------------------------------------------
// Merged QKV GEMM (round-7 exact). 768 blocks, bijective XCD swizzle.
//   orig < 512:  nsel 0/1 (q/k), coalesced bf16 stores.
//   orig >= 512: nsel 2 (v) OPERAND-SWAPPED so vt stores are coalesced.
// ---------------------------------------------------------------------------
__global__ __launch_bounds__(512)
void gemm_qkv8(const __hip_bfloat16* __restrict__ xb,
               const __hip_bfloat16* __restrict__ wq,
               const __hip_bfloat16* __restrict__ wk,
               const __hip_bfloat16* __restrict__ wv,
               __hip_bfloat16* __restrict__ q,
               __hip_bfloat16* __restrict__ k,
               __hip_bfloat16* __restrict__ vt)
{
    __shared__ __align__(16) short sA[3 * 4096];   // 24 KB
    __shared__ __align__(16) short sB[3 * 8192];   // 48 KB

    const int rb  = (int)blockIdx.x;
    const int bid = (rb & 7) * 96 + (rb >> 3);     // XCD chunking (768%8==0)
    int nsel, marow0, n0;
    const __hip_bfloat16 *Ap, *Bp;
    if (bid < 512) {
        nsel = bid >> 8;
        const int t = bid & 255;
        marow0 = (t >> 3) * 128;          // over 4096 x-rows
        n0     = (t & 7) * 256;           // over 2048 w-rows
        Ap = xb; Bp = nsel ? wk : wq;
    } else {
        nsel = 2;
        const int t = bid - 512;
        marow0 = (t >> 4) * 128;          // over 2048 wv-rows
        n0     = (t & 15) * 256;          // over 4096 x-rows
        Ap = wv; Bp = xb;
    }

    f32x4 acc[4][4];
    #pragma unroll
    for (int i = 0; i < 4; i++)
        #pragma unroll
        for (int j = 0; j < 4; j++) acc[i][j] = (f32x4)(0.0f);

    gemm8_main(Ap, Bp, marow0, n0, sA, sB, acc);

    const int tid = threadIdx.x, w = tid >> 6, lane = tid & 63;
    const int l15 = lane & 15, quad = lane >> 4;
    const int wm = w >> 2, wn = w & 3;

    #pragma unroll
    for (int mf = 0; mf < 4; mf++) {
        #pragma unroll
        for (int r = 0; r < 4; r++) {
            const int m = marow0 + wm * 64 + mf * 16 + quad * 4 + r;
            #pragma unroll
            for (int nf = 0; nf < 4; nf++) {
                const int n = n0 + wn * 64 + nf * 16 + l15;
                if (nsel < 2) {
                    const int b = m >> 11, s = m & 2047;
                    const int h = n >> 7,  dh = n & 127;
                    __hip_bfloat16* o = nsel ? k : q;
                    o[(((size_t)(b * 16 + h)) * 2048 + s) * 128 + dh] =
                        __float2bfloat16(acc[mf][nf][r]);
                } else {
                    const int h = m >> 7,  dh = m & 127;
                    const int b = n >> 11, sq = n & 2047;
                    vt[(((size_t)(b * 16 + h)) * 128 + dh) * 2048 + sq] =
                        __float2bfloat16(acc[mf][nf][r]);
                }
            }
        }
    }
}

// ---------------------------------------------------------------------------
// Final projection (round-7 exact): out[M,N] fp32 = vals[M,K] * Wo[N,K]^T.
// ---------------------------------------------------------------------------
__global__ __launch_bounds__(512)
void gemm_o8(const __hip_bfloat16* __restrict__ A,
             const __hip_bfloat16* __restrict__ W,
             float* __restrict__ out)
{
    __shared__ __align__(16) short sA[3 * 4096];
    __shared__ __align__(16) short sB[3 * 8192];

    const int rb  = (int)blockIdx.x;
    const int bid = (rb & 7) * 32 + (rb >> 3);     // 256 % 8 == 0
    const int marow0 = (bid >> 3) * 128;   // over 4096 rows
    const int n0     = (bid & 7) * 256;    // over 2048 cols

    f32x4 acc[4][4];
    #pragma unroll
    for (int i = 0; i < 4; i++)
        #pragma unroll
        for (int j = 0; j < 4; j++) acc[i][j] = (f32x4)(0.0f);

    gemm8_main(A, W, marow0, n0, sA, sB, acc);

    const int tid = threadIdx.x, w = tid >> 6, lane = tid & 63;
    const int l15 = lane & 15, quad = lane >> 4;
    const int wm = w >> 2, wn = w & 3;

    #pragma unroll
    for (int mf = 0; mf < 4; mf++) {
        #pragma unroll
        for (int r = 0; r < 4; r++) {
            const int m = marow0 + wm * 64 + mf * 16 + quad * 4 + r;
            #pragma unroll
            for (int nf = 0; nf < 4; nf++) {
                const int n = n0 + wn * 64 + nf * 16 + l15;
                out[(size_t)m * 2048 + n] = acc[mf][nf][r];
            }
        }
    }
}

// ---------------------------------------------------------------------------
// RoPE on q AND k in one launch; cos/sin fp32 [S, DH].
// ---------------------------------------------------------------------------
__global__ __launch_bounds__(256)
void rope2_kernel(__hip_bfloat16* __restrict__ q, __hip_bfloat16* __restrict__ k,
                  const float* __restrict__ cos_, const float* __restrict__ sin_,
                  int per)
{
    const int sel = blockIdx.x / per, rem = blockIdx.x % per;
    __hip_bfloat16* base = sel == 0 ? q : k;
    const size_t i = (size_t)rem * blockDim.x + threadIdx.x;
    const int dh = (int)(i & 63);
    const size_t row = i >> 6;
    const int s = (int)(row % S_);
    __hip_bfloat16* p = base + row * DH_;

    const float x1 = __bfloat162float(p[dh]);
    const float x2 = __bfloat162float(p[dh + 64]);
    const float c1 = cos_[s * DH_ + dh];
    const float s1 = sin_[s * DH_ + dh];
    const float c2 = cos_[s * DH_ + dh + 64];
    const float s2 = sin_[s * DH_ + dh + 64];

    p[dh]      = __float2bfloat16(x1 * c1 - x2 * s1);
    p[dh + 64] = __float2bfloat16(x2 * c2 + x1 * s2);
}

// ---------------------------------------------------------------------------
// Flash attention v5: 64-row q-tiles (4 waves x 16 rows), kv-tile 64,
// SINGLE-buffered K and V (41 KB LDS -> 3 blocks/CU, was 73 KB / 2).
//
// Why the double-buffer was wasteful: with the two-barrier schedule the
// next tile's DMA always has a compute phase to hide under, so the second
// buffer only cost occupancy:
//   QK -> softmax/P-write -> B1 -> stageK(next)   [sK safe: QK done at B1;
//        K lands at B2's implicit vmcnt(0), exposure = PV (~400cyc)]
//   -> PV -> B2 -> stageV(next)                   [sV safe: PV done at B2;
//        V lands at next B1, covered by QK+softmax (~700cyc)]
// Extra barrier per iter is paid for by 12 waves/CU (was 8) and true LPT
// backfill (1024 blocks on 768-slot residency).
// ---------------------------------------------------------------------------
#define PSTR 72

__global__ __launch_bounds__(256)
void attn_mfma(const __hip_bfloat16* __restrict__ q,
               const __hip_bfloat16* __restrict__ k,
               const __hip_bfloat16* __restrict__ vt,
               __hip_bfloat16* __restrict__ vals)
{
    __shared__ __align__(16) short sK[64 * 128];      // 16 KB
    __shared__ __align__(16) short sV[128 * 64];      // 16 KB
    __shared__ __align__(16) short sP[4 * 16 * PSTR]; //  9 KB

    const int idx   = (int)blockIdx.x;
    const int bh    = idx & 31;
    const int qtile = 31 - (idx >> 5);
    const int q0    = qtile * 64;
    const int tid   = threadIdx.x;
    const int w     = tid >> 6;
    const int lane  = tid & 63;
    const int l15   = lane & 15;
    const int quad  = lane >> 4;
    const int qb    = q0 + w * 16;

    bf16x8 qf[4];
    {
        const __hip_bfloat16* qrow =
            q + ((size_t)bh * S_ + qb + l15) * DH_ + quad * 8;
        #pragma unroll
        for (int c = 0; c < 4; c++)
            qf[c] = *(const bf16x8*)(qrow + c * 32);
    }

    f32x4 o[8];
    #pragma unroll
    for (int d = 0; d < 8; d++) o[d] = (f32x4)(0.0f);
    float mrow[4], lrow[4];
    #pragma unroll
    for (int r = 0; r < 4; r++) { mrow[r] = -1e30f; lrow[r] = 0.f; }

    const float scale = 0.08838834764831845f;
    const int niter = qtile + 1;

    const int krow_in = lane >> 4, kgran = lane & 15;
    const int vrow_in = lane >> 3, vgran = lane & 7;

    auto stageK = [&](int kv0) {
        #pragma unroll
        for (int t = 0; t < 4; t++) {
            const int c    = w * 4 + t;
            const int krow = c * 4 + krow_in;
            const int kcol = (kgran * 16) ^ ((krow & 7) << 4);
            async16(k + ((size_t)bh * S_ + kv0 + krow) * DH_ + (kcol >> 1),
                    sK + c * 512);
        }
    };
    auto stageV = [&](int kv0) {
        #pragma unroll
        for (int t = 0; t < 4; t++) {
            const int c    = w * 4 + t;
            const int vrow = c * 8 + vrow_in;
            const int vcol = (vgran * 16) ^ ((vrow & 7) << 4);
            async16(vt + ((size_t)bh * DH_ + vrow) * S_ + kv0 + (vcol >> 1),
                    sV + c * 512);
        }
    };

    stageK(0);
    stageV(0);
    __syncthreads();   // drains DMA: K(0), V(0) landed

    for (int it = 0; it < niter; ++it) {
        const int kv0 = it * 64;
        const int xsw = (l15 & 7) << 3;

        // QK^T from sK
        f32x4 s[4];
        #pragma unroll
        for (int n = 0; n < 4; n++) s[n] = (f32x4)(0.0f);
        #pragma unroll
        for (int n = 0; n < 4; n++) {
            const short* kp = sK + (n * 16 + l15) * 128;
            #pragma unroll
            for (int c = 0; c < 4; c++) {
                bf16x8 kf = *(const bf16x8*)(kp + ((quad * 8 + c * 32) ^ xsw));
                s[n] = __builtin_amdgcn_mfma_f32_16x16x32_bf16(qf[c], kf, s[n], 0, 0, 0);
            }
        }

        // softmax (online, deferred l-reduce) + P write
        {
            const bool msk = (kv0 + 63 > qb);
            float sv[4][4];
            #pragma unroll
            for (int n = 0; n < 4; n++)
                #pragma unroll
                for (int r = 0; r < 4; r++) {
                    float x = s[n][r] * scale;
                    if (msk) {
                        const int kvg = kv0 + n * 16 + l15;
                        const int qg  = qb + quad * 4 + r;
                        if (kvg > qg) x = -1e30f;
                    }
                    sv[n][r] = x;
                }

            float alpha[4];
            #pragma unroll
            for (int r = 0; r < 4; r++) {
                float v = fmaxf(fmaxf(sv[0][r], sv[1][r]), fmaxf(sv[2][r], sv[3][r]));
                #pragma unroll
                for (int m2 = 8; m2; m2 >>= 1)
                    v = fmaxf(v, __shfl_xor(v, m2, 64));
                const float mn = fmaxf(mrow[r], v);
                alpha[r] = __expf(mrow[r] - mn);
                mrow[r] = mn;
            }
            #pragma unroll
            for (int r = 0; r < 4; r++) {
                float rs = 0.f;
                #pragma unroll
                for (int n = 0; n < 4; n++) {
                    const float p = __expf(sv[n][r] - mrow[r]);
                    sv[n][r] = p;
                    rs += p;
                }
                lrow[r] = lrow[r] * alpha[r] + rs;
            }
            #pragma unroll
            for (int d = 0; d < 8; d++)
                #pragma unroll
                for (int r = 0; r < 4; r++)
                    o[d][r] *= alpha[r];

            short* pb = &sP[(w * 16) * PSTR];
            #pragma unroll
            for (int n = 0; n < 4; n++)
                #pragma unroll
                for (int r = 0; r < 4; r++)
                    pb[(quad * 4 + r) * PSTR + n * 16 + l15] = bf16bits(sv[n][r]);
        }

        __syncthreads();   // B1: P ready; all waves done with sK; V(it) landed

        if (it + 1 < niter) stageK(kv0 + 64);   // sK safe (QK done)

        // PV from sV & sP
        #pragma unroll
        for (int c = 0; c < 2; c++) {
            bf16x8 pf = *(const bf16x8*)(&sP[(w * 16 + l15) * PSTR + c * 32 + quad * 8]);
            #pragma unroll
            for (int d = 0; d < 8; d++) {
                bf16x8 vf = *(const bf16x8*)(sV + (d * 16 + l15) * 64 +
                                             ((quad * 8 + c * 32) ^ xsw));
                o[d] = __builtin_amdgcn_mfma_f32_16x16x32_bf16(pf, vf, o[d], 0, 0, 0);
            }
        }

        __syncthreads();   // B2: all waves done with sV; K(next) landed

        if (it + 1 < niter) stageV(kv0 + 64);   // sV safe (PV done)
    }

    const int b = bh >> 4, h = bh & 15;
    #pragma unroll
    for (int r = 0; r < 4; r++) {
        float l = lrow[r];
        #pragma unroll
        for (int m2 = 8; m2; m2 >>= 1)
            l += __shfl_xor(l, m2, 64);
        const float inv = 1.0f / l;
        const int qg = qb + quad * 4 + r;
        #pragma unroll
        for (int d = 0; d < 8; d++) {
            const int col = d * 16 + l15;
            vals[(((size_t)b * S_ + qg) * H_ + h) * DH_ + col] =
                __float2bfloat16(o[d][r] * inv);
        }
    }
}

// ---------------------------------------------------------------------------
extern "C" void kernel_launch(void* const* d_in, const int* in_sizes, int n_in,
                              void* d_out, int out_size, void* d_ws, size_t ws_size,
                              hipStream_t stream)
{
    const float* x    = (const float*)d_in[0];
    const float* cos_ = (const float*)d_in[1];
    const float* sin_ = (const float*)d_in[2];
    const float* Wq   = (const float*)d_in[3];
    const float* Wk   = (const float*)d_in[4];
    const float* Wv   = (const float*)d_in[5];
    const float* Wo   = (const float*)d_in[6];
    float* out = (float*)d_out;

    const size_t NELEM = (size_t)B_ * S_ * D_;       // 8388608
    const size_t WELEM = (size_t)D_ * D_;            // 4194304

    // d_out scratch during QKV phase: 3 bf16 weights (25.2 MB <= 33.5 MB)
    __hip_bfloat16* wqb = (__hip_bfloat16*)d_out;
    __hip_bfloat16* wkb = wqb + WELEM;
    __hip_bfloat16* wvb = wkb + WELEM;
    // ws (67 MB): q,k,vt,vals. xb shares the vals region (dead before attn
    // writes vals); Wo-bf16 reuses q region (dead after attn).
    __hip_bfloat16* q    = (__hip_bfloat16*)d_ws;
    __hip_bfloat16* k    = q + NELEM;
    __hip_bfloat16* vt   = k + NELEM;
    __hip_bfloat16* vals = vt + NELEM;
    __hip_bfloat16* xb   = vals;
    __hip_bfloat16* wob  = q;

    const int xcb = (int)(NELEM / (256 * 8));        // 4096 blocks
    const int wcb = (int)(WELEM / (256 * 8));        // 2048 blocks

    f2b_kernel<<<xcb, 256, 0, stream>>>(x, xb);
    f2b3_kernel<<<3 * wcb, 256, 0, stream>>>(Wq, Wk, Wv, wqb, wkb, wvb, wcb);

    // 512 q/k blocks + 256 swapped-v blocks = 768
    gemm_qkv8<<<768, 512, 0, stream>>>(xb, wqb, wkb, wvb, q, k, vt);

    const int rope_blocks = B_ * H_ * S_ * 64 / 256;  // per tensor
    rope2_kernel<<<2 * rope_blocks, 256, 0, stream>>>(q, k, cos_, sin_, rope_blocks);

    // 32 qtiles x 32 bh, longest-first for LPT backfill
    attn_mfma<<<dim3(32 * (B_ * H_)), 256, 0, stream>>>(q, k, vt, vals);

    f2b_kernel<<<wcb, 256, 0, stream>>>(Wo, wob);
    gemm_o8<<<256, 512, 0, stream>>>(vals, wob, out);
}